// Round 20
// baseline (23.212 us; speedup 1.0000x reference)
//
#include <hip/hip_runtime.h>
#include <hip/hip_bf16.h>
#include <cstdint>

// VQ-VAE vector quantize: N=65536 vectors, D=64, K=512 codes.
// d_in[0]: inputs fp32 [65536,64], d_in[1]: embeddings fp32 [512,64]
// d_out: [0]=loss, [1..4194304]=latent (gathered fp32 embeddings)
//
// R20: R18 (21.0us; 256 blocks x 512 threads, 4 iters, wave-owned 64-code
// B slice in VGPRs) + deferred epilogue: per iter only the cmb read +
// packed-min winner lands in registers; all emb gathers + latent stores
// batch after the loop (8 independent L2 loads, ILP-overlapped).

typedef __attribute__((ext_vector_type(8))) short bf16x8;
typedef __attribute__((ext_vector_type(4))) float f32x4;

#define NITER 4

__device__ __forceinline__ short f2bf(float f) {
    uint32_t u = __builtin_bit_cast(uint32_t, f);
    u += 0x7FFFu + ((u >> 16) & 1u);   // round-to-nearest-even
    return (short)(u >> 16);
}

__device__ __forceinline__ float sumsq4(float4 v, float acc) {
    return fmaf(v.x, v.x, fmaf(v.y, v.y, fmaf(v.z, v.z, fmaf(v.w, v.w, acc))));
}

__device__ __forceinline__ bf16x8 packpos(float4 a, float4 b) {
    bf16x8 f;
    f[0] = f2bf(a.x); f[1] = f2bf(a.y); f[2] = f2bf(a.z); f[3] = f2bf(a.w);
    f[4] = f2bf(b.x); f[5] = f2bf(b.y); f[6] = f2bf(b.z); f[7] = f2bf(b.w);
    return f;
}

// ws layout (bytes):
//  [0, 65536)     : B fragments bf16(-e), [ct(32)][ks(2)][lane(64)] x 16B
//  [65536, 67584) : ee_t[512] fp32 = 0.5*||e_k||^2, TRANSPOSED [cb(16)][ct(32)]
//  [67584, 68608) : partials[256] fp32
#define WS_EE   65536
#define WS_PART 67584

// ---------------- Kernel 1: setup (16 blocks x 256) ----------------
__global__ __launch_bounds__(256)
void vq_setup(const float* __restrict__ emb, char* __restrict__ ws) {
    const int tid = threadIdx.x, bid = blockIdx.x;
    bf16x8* bfrag = (bf16x8*)ws;
    float* eet = (float*)(ws + WS_EE);

    const int s = bid * 256 + tid;
    const int ct = s >> 7, ks = (s >> 6) & 1, ln = s & 63;
    const int code = (ct << 4) | (ln & 15);
    const int d0 = ks * 32 + ((ln >> 4) << 3);
    const float* src = emb + code * 64 + d0;
    float4 v0 = *(const float4*)src;
    float4 v1 = *(const float4*)(src + 4);
    bf16x8 b;
    b[0] = f2bf(-v0.x); b[1] = f2bf(-v0.y); b[2] = f2bf(-v0.z); b[3] = f2bf(-v0.w);
    b[4] = f2bf(-v1.x); b[5] = f2bf(-v1.y); b[6] = f2bf(-v1.z); b[7] = f2bf(-v1.w);
    bfrag[s] = b;

    if (tid < 32) {
        const int c = bid * 32 + tid;
        const float4* e4 = (const float4*)(emb + c * 64);
        float acc = 0.f;
        #pragma unroll
        for (int q = 0; q < 16; ++q) {
            float4 v = e4[q];
            acc = fmaf(v.x, v.x, fmaf(v.y, v.y, fmaf(v.z, v.z, fmaf(v.w, v.w, acc))));
        }
        eet[(c & 15) * 32 + (c >> 4)] = 0.5f * acc;   // transposed, pre-halved
    }
}

// ---------------- Kernel 2: main (256 blocks x 512) ----------------
// Block owns 256 rows (4 iters x 64). Wave w holds codes [w*64,(w+1)*64)
// in 32 VGPRs; stages A slot (rt=w>>1, ks=w&1); 8-way LDS combine.
__global__ __launch_bounds__(512)
void vq_main(const float* __restrict__ flat, const float* __restrict__ emb,
             char* __restrict__ ws, float* __restrict__ out) {
    __shared__ bf16x8 albuf[2][4][2][64];   // 16 KB [buf][rt][ks][lane]
    __shared__ float  cmb[2][8][64];        // 4 KB  [buf][wave][row]
    __shared__ float  red[8];

    const int tid = threadIdx.x, bid = blockIdx.x;
    const int lane = tid & 63, wid = tid >> 6;      // 8 waves
    const int cb = lane & 15, g = lane >> 4;
    const int rb = bid * 256;                       // block's 256 rows
    const int srt = wid >> 1, sks = wid & 1;        // this wave's staging slot
    const char* wsg = (const char*)ws;

    // ---- A iter-0 loads: wave's staging slot (16 rows x 32 dims) ----
    const float* a0src = flat + (long)(rb + srt * 16 + cb) * 64 + sks * 32 + (g << 3);
    float4 ar0 = *(const float4*)a0src;
    float4 ar1 = *(const float4*)(a0src + 4);

    // ---- B slice: wave's 4 col-tiles -> 32 VGPRs, loaded once ----
    const bf16x8* wsb = (const bf16x8*)wsg;
    bf16x8 bv[4][2];
    #pragma unroll
    for (int c = 0; c < 4; ++c) {
        bv[c][0] = wsb[(wid * 4 + c) * 128 + lane];
        bv[c][1] = wsb[(wid * 4 + c) * 128 + 64 + lane];
    }

    // ---- half-norms for this wave's 4 col-tiles, this lane's col class ----
    float hvv[4];
    {
        float4 h = *(const float4*)(wsg + WS_EE + cb * 128 + wid * 16);
        hvv[0] = h.x; hvv[1] = h.y; hvv[2] = h.z; hvv[3] = h.w;
    }

    // ---- iter-0: ||x||^2 partial + convert + stage albuf[0] ----
    float xx = 0.f;
    xx = sumsq4(ar0, xx); xx = sumsq4(ar1, xx);
    albuf[0][srt][sks][lane] = packpos(ar0, ar1);
    __syncthreads();

    uint32_t mbarr[NITER];   // per-iter winning packed min for my row

    #pragma unroll
    for (int it = 0; it < NITER; ++it) {
        // prefetch next iter's staging slot under this iter's compute
        float4 br0, br1;
        if (it < NITER - 1) {
            const float* asrc = flat + (long)(rb + (it + 1) * 64 + srt * 16 + cb) * 64
                                + sks * 32 + (g << 3);
            br0 = *(const float4*)asrc;
            br1 = *(const float4*)(asrc + 4);
        }

        // ---- compute: 4 row-tiles x 4 code-tiles, B from VGPRs ----
        // two partial accumulators halve the fminf dependency depth
        float pmA[4][4], pmB[4][4];
        #pragma unroll
        for (int rt = 0; rt < 4; ++rt) {
            bf16x8 a0 = albuf[it & 1][rt][0][lane];
            bf16x8 a1 = albuf[it & 1][rt][1][lane];
            #pragma unroll
            for (int c = 0; c < 4; ++c) {
                const float h = hvv[c];
                const int colv = ((wid * 4 + c) << 4) | cb;
                f32x4 acc = {h, h, h, h};    // 0.5||e||^2 - x.e   (B = -e)
                acc = __builtin_amdgcn_mfma_f32_16x16x32_bf16(a0, bv[c][0], acc, 0, 0, 0);
                acc = __builtin_amdgcn_mfma_f32_16x16x32_bf16(a1, bv[c][1], acc, 0, 0, 0);
                #pragma unroll
                for (int j = 0; j < 4; ++j) {
                    float dp = __builtin_bit_cast(float,
                        (__builtin_bit_cast(uint32_t, acc[j]) & 0xFFFFFE00u) | (uint32_t)colv);
                    if (c == 0)      pmA[rt][j] = dp;
                    else if (c == 1) pmB[rt][j] = dp;
                    else if (c == 2) pmA[rt][j] = fminf(pmA[rt][j], dp);
                    else             pmB[rt][j] = fminf(pmB[rt][j], dp);
                }
            }
        }
        float pm[4][4];
        #pragma unroll
        for (int rt = 0; rt < 4; ++rt)
            #pragma unroll
            for (int j = 0; j < 4; ++j)
                pm[rt][j] = fminf(pmA[rt][j], pmB[rt][j]);

        // ---- butterfly min over the 16 column-class lanes ----
        #pragma unroll
        for (int m = 1; m < 16; m <<= 1) {
            #pragma unroll
            for (int rt = 0; rt < 4; ++rt)
                #pragma unroll
                for (int j = 0; j < 4; ++j)
                    pm[rt][j] = fminf(pm[rt][j], __shfl_xor(pm[rt][j], m, 64));
        }
        if (cb == 0) {
            #pragma unroll
            for (int rt = 0; rt < 4; ++rt)
                #pragma unroll
                for (int j = 0; j < 4; ++j)
                    cmb[it & 1][wid][rt * 16 + g * 4 + j] = pm[rt][j];
        }

        // ---- stage next iter's A (rotating buffer, WAR-safe) ----
        if (it < NITER - 1) {
            xx = sumsq4(br0, xx); xx = sumsq4(br1, xx);
            albuf[(it + 1) & 1][srt][sks][lane] = packpos(br0, br1);
        }
        __syncthreads();   // cmb[it&1] + albuf[(it+1)&1] visible

        // ---- light epilogue: winner only (global gather deferred) ----
        const int row = tid >> 3;
        float mn = cmb[it & 1][0][row];
        #pragma unroll
        for (int w = 1; w < 8; ++w) mn = fminf(mn, cmb[it & 1][w][row]);
        mbarr[it] = __builtin_bit_cast(uint32_t, mn);
    }

    // ---- deferred epilogue: 4 iters' gathers + stores, ILP-overlapped ----
    const int row = tid >> 3, seg = tid & 7;
    float dacc = 0.f;
    float4 ev[NITER][2];
    #pragma unroll
    for (int it = 0; it < NITER; ++it) {
        const int ix = (int)(mbarr[it] & 0x1FFu);
        const float4* esrc = (const float4*)(emb + ix * 64 + seg * 8);
        ev[it][0] = esrc[0];
        ev[it][1] = esrc[1];
    }
    #pragma unroll
    for (int it = 0; it < NITER; ++it) {
        float* ob = out + 1 + (long)(rb + it * 64 + row) * 64 + seg * 8;
        float4 e0 = ev[it][0], e1 = ev[it][1];
        ob[0] = e0.x; ob[1] = e0.y; ob[2] = e0.z; ob[3] = e0.w;
        ob[4] = e1.x; ob[5] = e1.y; ob[6] = e1.z; ob[7] = e1.w;
        if (seg == 0) dacc += __builtin_bit_cast(float, mbarr[it] & 0xFFFFFE00u);
    }

    // ---- loss partial: sum_threads( xx + 2*dacc ) ----
    float t = fmaf(2.f, dacc, xx);
    #pragma unroll
    for (int m = 32; m; m >>= 1) t += __shfl_down(t, m, 64);
    if (lane == 0) red[wid] = t;
    __syncthreads();
    if (tid == 0) {
        float s = 0.f;
        #pragma unroll
        for (int i = 0; i < 8; ++i) s += red[i];
        ((float*)(ws + WS_PART))[bid] = s;
    }
}

// ---------------- Kernel 3: deterministic final reduce (1 block) ----------------
__global__ __launch_bounds__(256)
void vq_loss(const float* __restrict__ partials, float* __restrict__ out) {
    __shared__ float red[4];
    const int tid = threadIdx.x;
    float acc = partials[tid];
    #pragma unroll
    for (int m = 32; m; m >>= 1) acc += __shfl_down(acc, m, 64);
    if ((tid & 63) == 0) red[tid >> 6] = acc;
    __syncthreads();
    // loss = 0.25*e_loss + q_loss = 1.25 * mse (forward)
    if (tid == 0) out[0] = 1.25f * (red[0] + red[1] + red[2] + red[3]) / 4194304.0f;
}

extern "C" void kernel_launch(void* const* d_in, const int* in_sizes, int n_in,
                              void* d_out, int out_size, void* d_ws, size_t ws_size,
                              hipStream_t stream) {
    const float* flat = (const float*)d_in[0];   // [65536,64]
    const float* emb  = (const float*)d_in[1];   // [512,64]
    float* out = (float*)d_out;
    char* ws = (char*)d_ws;

    vq_setup<<<16, 256, 0, stream>>>(emb, ws);
    vq_main<<<256, 512, 0, stream>>>(flat, emb, ws, out);
    vq_loss<<<1, 256, 0, stream>>>((const float*)(ws + WS_PART), out);
}

// Round 21
// 21.033 us; speedup vs baseline: 1.1036x; 1.1036x over previous
//
#include <hip/hip_runtime.h>
#include <hip/hip_bf16.h>
#include <cstdint>

// VQ-VAE vector quantize: N=65536 vectors, D=64, K=512 codes.
// d_in[0]: inputs fp32 [65536,64], d_in[1]: embeddings fp32 [512,64]
// d_out: [0]=loss, [1..4194304]=latent (gathered fp32 embeddings)
//
// R21 = R18 verbatim (measured session best: 21.04 us).
// 256 blocks x 512 threads (8 waves = 2/SIMD), 256 rows/block in 4 iters
// of 64. Wave w owns a 64-code B slice (4 col-tiles, 32 VGPRs, loaded once);
// A staged 8-way (slot rt=w>>1, ks=w&1); iter i+1 A-loads prefetched under
// iter i's compute; rotating albuf/cmb (WAR-safe); per-iter epilogue
// (overlaps across waves - R20 showed deferring it regresses).
// No cross-block atomics (R8/R14); 3-kernel chain for the loss combine.

typedef __attribute__((ext_vector_type(8))) short bf16x8;
typedef __attribute__((ext_vector_type(4))) float f32x4;

#define NITER 4

__device__ __forceinline__ short f2bf(float f) {
    uint32_t u = __builtin_bit_cast(uint32_t, f);
    u += 0x7FFFu + ((u >> 16) & 1u);   // round-to-nearest-even
    return (short)(u >> 16);
}

__device__ __forceinline__ float sumsq4(float4 v, float acc) {
    return fmaf(v.x, v.x, fmaf(v.y, v.y, fmaf(v.z, v.z, fmaf(v.w, v.w, acc))));
}

__device__ __forceinline__ bf16x8 packpos(float4 a, float4 b) {
    bf16x8 f;
    f[0] = f2bf(a.x); f[1] = f2bf(a.y); f[2] = f2bf(a.z); f[3] = f2bf(a.w);
    f[4] = f2bf(b.x); f[5] = f2bf(b.y); f[6] = f2bf(b.z); f[7] = f2bf(b.w);
    return f;
}

// ws layout (bytes):
//  [0, 65536)     : B fragments bf16(-e), [ct(32)][ks(2)][lane(64)] x 16B
//  [65536, 67584) : ee_t[512] fp32 = 0.5*||e_k||^2, TRANSPOSED [cb(16)][ct(32)]
//  [67584, 68608) : partials[256] fp32
#define WS_EE   65536
#define WS_PART 67584

// ---------------- Kernel 1: setup (16 blocks x 256) ----------------
__global__ __launch_bounds__(256)
void vq_setup(const float* __restrict__ emb, char* __restrict__ ws) {
    const int tid = threadIdx.x, bid = blockIdx.x;
    bf16x8* bfrag = (bf16x8*)ws;
    float* eet = (float*)(ws + WS_EE);

    const int s = bid * 256 + tid;
    const int ct = s >> 7, ks = (s >> 6) & 1, ln = s & 63;
    const int code = (ct << 4) | (ln & 15);
    const int d0 = ks * 32 + ((ln >> 4) << 3);
    const float* src = emb + code * 64 + d0;
    float4 v0 = *(const float4*)src;
    float4 v1 = *(const float4*)(src + 4);
    bf16x8 b;
    b[0] = f2bf(-v0.x); b[1] = f2bf(-v0.y); b[2] = f2bf(-v0.z); b[3] = f2bf(-v0.w);
    b[4] = f2bf(-v1.x); b[5] = f2bf(-v1.y); b[6] = f2bf(-v1.z); b[7] = f2bf(-v1.w);
    bfrag[s] = b;

    if (tid < 32) {
        const int c = bid * 32 + tid;
        const float4* e4 = (const float4*)(emb + c * 64);
        float acc = 0.f;
        #pragma unroll
        for (int q = 0; q < 16; ++q) {
            float4 v = e4[q];
            acc = fmaf(v.x, v.x, fmaf(v.y, v.y, fmaf(v.z, v.z, fmaf(v.w, v.w, acc))));
        }
        eet[(c & 15) * 32 + (c >> 4)] = 0.5f * acc;   // transposed, pre-halved
    }
}

// ---------------- Kernel 2: main (256 blocks x 512) ----------------
// Block owns 256 rows (4 iters x 64). Wave w holds codes [w*64,(w+1)*64)
// in 32 VGPRs; stages A slot (rt=w>>1, ks=w&1); 8-way LDS combine.
__global__ __launch_bounds__(512)
void vq_main(const float* __restrict__ flat, const float* __restrict__ emb,
             char* __restrict__ ws, float* __restrict__ out) {
    __shared__ bf16x8 albuf[2][4][2][64];   // 16 KB [buf][rt][ks][lane]
    __shared__ float  cmb[2][8][64];        // 4 KB  [buf][wave][row]
    __shared__ float  red[8];

    const int tid = threadIdx.x, bid = blockIdx.x;
    const int lane = tid & 63, wid = tid >> 6;      // 8 waves
    const int cb = lane & 15, g = lane >> 4;
    const int rb = bid * 256;                       // block's 256 rows
    const int srt = wid >> 1, sks = wid & 1;        // this wave's staging slot
    const char* wsg = (const char*)ws;

    // ---- A iter-0 loads: wave's staging slot (16 rows x 32 dims) ----
    const float* a0src = flat + (long)(rb + srt * 16 + cb) * 64 + sks * 32 + (g << 3);
    float4 ar0 = *(const float4*)a0src;
    float4 ar1 = *(const float4*)(a0src + 4);

    // ---- B slice: wave's 4 col-tiles -> 32 VGPRs, loaded once ----
    const bf16x8* wsb = (const bf16x8*)wsg;
    bf16x8 bv[4][2];
    #pragma unroll
    for (int c = 0; c < 4; ++c) {
        bv[c][0] = wsb[(wid * 4 + c) * 128 + lane];
        bv[c][1] = wsb[(wid * 4 + c) * 128 + 64 + lane];
    }

    // ---- half-norms for this wave's 4 col-tiles, this lane's col class ----
    float hvv[4];
    {
        float4 h = *(const float4*)(wsg + WS_EE + cb * 128 + wid * 16);
        hvv[0] = h.x; hvv[1] = h.y; hvv[2] = h.z; hvv[3] = h.w;
    }

    // ---- iter-0: ||x||^2 partial + convert + stage albuf[0] ----
    float xx = 0.f;
    xx = sumsq4(ar0, xx); xx = sumsq4(ar1, xx);
    albuf[0][srt][sks][lane] = packpos(ar0, ar1);
    __syncthreads();

    float dacc = 0.f;   // sum of winning dist' for my epilogue rows

    #pragma unroll
    for (int it = 0; it < NITER; ++it) {
        // prefetch next iter's staging slot under this iter's compute
        float4 br0, br1;
        if (it < NITER - 1) {
            const float* asrc = flat + (long)(rb + (it + 1) * 64 + srt * 16 + cb) * 64
                                + sks * 32 + (g << 3);
            br0 = *(const float4*)asrc;
            br1 = *(const float4*)(asrc + 4);
        }

        // ---- compute: 4 row-tiles x 4 code-tiles, B from VGPRs ----
        float pm[4][4];
        #pragma unroll
        for (int rt = 0; rt < 4; ++rt)
            #pragma unroll
            for (int j = 0; j < 4; ++j) pm[rt][j] = __builtin_bit_cast(float, 0x7F800000u);

        #pragma unroll
        for (int rt = 0; rt < 4; ++rt) {
            bf16x8 a0 = albuf[it & 1][rt][0][lane];
            bf16x8 a1 = albuf[it & 1][rt][1][lane];
            #pragma unroll
            for (int c = 0; c < 4; ++c) {
                const float h = hvv[c];
                const int colv = ((wid * 4 + c) << 4) | cb;
                f32x4 acc = {h, h, h, h};    // 0.5||e||^2 - x.e   (B = -e)
                acc = __builtin_amdgcn_mfma_f32_16x16x32_bf16(a0, bv[c][0], acc, 0, 0, 0);
                acc = __builtin_amdgcn_mfma_f32_16x16x32_bf16(a1, bv[c][1], acc, 0, 0, 0);
                #pragma unroll
                for (int j = 0; j < 4; ++j) {
                    uint32_t dp = (__builtin_bit_cast(uint32_t, acc[j]) & 0xFFFFFE00u) | (uint32_t)colv;
                    pm[rt][j] = fminf(pm[rt][j], __builtin_bit_cast(float, dp));
                }
            }
        }

        // ---- butterfly min over the 16 column-class lanes ----
        #pragma unroll
        for (int m = 1; m < 16; m <<= 1) {
            #pragma unroll
            for (int rt = 0; rt < 4; ++rt)
                #pragma unroll
                for (int j = 0; j < 4; ++j)
                    pm[rt][j] = fminf(pm[rt][j], __shfl_xor(pm[rt][j], m, 64));
        }
        if (cb == 0) {
            #pragma unroll
            for (int rt = 0; rt < 4; ++rt)
                #pragma unroll
                for (int j = 0; j < 4; ++j)
                    cmb[it & 1][wid][rt * 16 + g * 4 + j] = pm[rt][j];
        }

        // ---- stage next iter's A (rotating buffer, WAR-safe) ----
        if (it < NITER - 1) {
            xx = sumsq4(br0, xx); xx = sumsq4(br1, xx);
            albuf[(it + 1) & 1][srt][sks][lane] = packpos(br0, br1);
        }
        __syncthreads();   // cmb[it&1] + albuf[(it+1)&1] visible

        // ---- epilogue: row = tid>>3 (0..63), seg = tid&7 (8 floats) ----
        const int row = tid >> 3, seg = tid & 7;
        float mn = cmb[it & 1][0][row];
        #pragma unroll
        for (int w = 1; w < 8; ++w) mn = fminf(mn, cmb[it & 1][w][row]);
        const uint32_t mbits = __builtin_bit_cast(uint32_t, mn);
        const int ix = (int)(mbits & 0x1FFu);

        const float4* esrc = (const float4*)(emb + ix * 64 + seg * 8);
        float4 e0 = esrc[0], e1 = esrc[1];
        float* ob = out + 1 + (long)(rb + it * 64 + row) * 64 + seg * 8;
        ob[0] = e0.x; ob[1] = e0.y; ob[2] = e0.z; ob[3] = e0.w;
        ob[4] = e1.x; ob[5] = e1.y; ob[6] = e1.z; ob[7] = e1.w;

        if (seg == 0) dacc += __builtin_bit_cast(float, mbits & 0xFFFFFE00u);
    }

    // ---- loss partial: sum_threads( xx + 2*dacc ) ----
    float t = fmaf(2.f, dacc, xx);
    #pragma unroll
    for (int m = 32; m; m >>= 1) t += __shfl_down(t, m, 64);
    if (lane == 0) red[wid] = t;
    __syncthreads();
    if (tid == 0) {
        float s = 0.f;
        #pragma unroll
        for (int i = 0; i < 8; ++i) s += red[i];
        ((float*)(ws + WS_PART))[bid] = s;
    }
}

// ---------------- Kernel 3: deterministic final reduce (1 block) ----------------
__global__ __launch_bounds__(256)
void vq_loss(const float* __restrict__ partials, float* __restrict__ out) {
    __shared__ float red[4];
    const int tid = threadIdx.x;
    float acc = partials[tid];
    #pragma unroll
    for (int m = 32; m; m >>= 1) acc += __shfl_down(acc, m, 64);
    if ((tid & 63) == 0) red[tid >> 6] = acc;
    __syncthreads();
    // loss = 0.25*e_loss + q_loss = 1.25 * mse (forward)
    if (tid == 0) out[0] = 1.25f * (red[0] + red[1] + red[2] + red[3]) / 4194304.0f;
}

extern "C" void kernel_launch(void* const* d_in, const int* in_sizes, int n_in,
                              void* d_out, int out_size, void* d_ws, size_t ws_size,
                              hipStream_t stream) {
    const float* flat = (const float*)d_in[0];   // [65536,64]
    const float* emb  = (const float*)d_in[1];   // [512,64]
    float* out = (float*)d_out;
    char* ws = (char*)d_ws;

    vq_setup<<<16, 256, 0, stream>>>(emb, ws);
    vq_main<<<256, 512, 0, stream>>>(flat, emb, ws, out);
    vq_loss<<<1, 256, 0, stream>>>((const float*)(ws + WS_PART), out);
}

// Round 22
// 19.756 us; speedup vs baseline: 1.1749x; 1.0646x over previous
//
#include <hip/hip_runtime.h>
#include <hip/hip_bf16.h>
#include <cstdint>

// VQ-VAE vector quantize: N=65536 vectors, D=64, K=512 codes.
// d_in[0]: inputs fp32 [65536,64], d_in[1]: embeddings fp32 [512,64]
// d_out: [0]=loss, [1..4194304]=latent (gathered fp32 embeddings)
//
// R22: R18 structure (21.0us) with the setup kernel eliminated. Each wave
// builds its OWN 64-code B slice (4 col-tiles) + norms directly from emb
// in-register (16 float4 L2 loads + 64 f2bf + 2 shfl_xor) — half the
// rebuild work of R12's failed attempt, and it overlaps the A-load latency.
// 2 kernels: vq_main + 1-block vq_loss. No cross-block atomics.

typedef __attribute__((ext_vector_type(8))) short bf16x8;
typedef __attribute__((ext_vector_type(4))) float f32x4;

#define NITER 4

__device__ __forceinline__ short f2bf(float f) {
    uint32_t u = __builtin_bit_cast(uint32_t, f);
    u += 0x7FFFu + ((u >> 16) & 1u);   // round-to-nearest-even
    return (short)(u >> 16);
}

__device__ __forceinline__ float sumsq4(float4 v, float acc) {
    return fmaf(v.x, v.x, fmaf(v.y, v.y, fmaf(v.z, v.z, fmaf(v.w, v.w, acc))));
}

__device__ __forceinline__ bf16x8 packpos(float4 a, float4 b) {
    bf16x8 f;
    f[0] = f2bf(a.x); f[1] = f2bf(a.y); f[2] = f2bf(a.z); f[3] = f2bf(a.w);
    f[4] = f2bf(b.x); f[5] = f2bf(b.y); f[6] = f2bf(b.z); f[7] = f2bf(b.w);
    return f;
}

__device__ __forceinline__ bf16x8 packneg(float4 a, float4 b) {
    bf16x8 f;
    f[0] = f2bf(-a.x); f[1] = f2bf(-a.y); f[2] = f2bf(-a.z); f[3] = f2bf(-a.w);
    f[4] = f2bf(-b.x); f[5] = f2bf(-b.y); f[6] = f2bf(-b.z); f[7] = f2bf(-b.w);
    return f;
}

// ---------------- Kernel 1: main (256 blocks x 512) ----------------
// Block owns 256 rows (4 iters x 64). Wave w owns codes [w*64,(w+1)*64):
// builds bf16(-e) fragments + 0.5||e||^2 in-register from emb, then the
// R18 loop: A staged 8-way (slot rt=w>>1, ks=w&1), prefetch, rotating
// albuf/cmb, per-iter epilogue.
__global__ __launch_bounds__(512)
void vq_main(const float* __restrict__ flat, const float* __restrict__ emb,
             float* __restrict__ partials, float* __restrict__ out) {
    __shared__ bf16x8 albuf[2][4][2][64];   // 16 KB [buf][rt][ks][lane]
    __shared__ float  cmb[2][8][64];        // 4 KB  [buf][wave][row]
    __shared__ float  red[8];

    const int tid = threadIdx.x, bid = blockIdx.x;
    const int lane = tid & 63, wid = tid >> 6;      // 8 waves
    const int cb = lane & 15, g = lane >> 4;
    const int rb = bid * 256;                       // block's 256 rows
    const int srt = wid >> 1, sks = wid & 1;        // this wave's staging slot

    // ---- A iter-0 loads: wave's staging slot (16 rows x 32 dims) ----
    const float* a0src = flat + (long)(rb + srt * 16 + cb) * 64 + sks * 32 + (g << 3);
    float4 ar0 = *(const float4*)a0src;
    float4 ar1 = *(const float4*)(a0src + 4);

    // ---- B slice: build bf16(-e) fragments + norms from emb (L2-hot) ----
    bf16x8 bv[4][2];
    float hvv[4];
    #pragma unroll
    for (int c = 0; c < 4; ++c) {
        const int code = ((wid * 4 + c) << 4) | cb;
        const float* es = emb + code * 64 + (g << 3);
        float4 v0 = *(const float4*)(es);
        float4 v1 = *(const float4*)(es + 4);
        float4 w0 = *(const float4*)(es + 32);
        float4 w1 = *(const float4*)(es + 36);
        float n = sumsq4(v0, 0.f); n = sumsq4(v1, n);
        n = sumsq4(w0, n);         n = sumsq4(w1, n);
        hvv[c] = n;                       // partial: this lane's 16 dims
        bv[c][0] = packneg(v0, v1);
        bv[c][1] = packneg(w0, w1);
    }
    // butterfly over the 4 lane-groups holding each code's 64 dims
    #pragma unroll
    for (int c = 0; c < 4; ++c) {
        float n = hvv[c];
        n += __shfl_xor(n, 16, 64);
        n += __shfl_xor(n, 32, 64);
        hvv[c] = 0.5f * n;                // 0.5*||e||^2, full
    }

    // ---- iter-0: ||x||^2 partial + convert + stage albuf[0] ----
    float xx = 0.f;
    xx = sumsq4(ar0, xx); xx = sumsq4(ar1, xx);
    albuf[0][srt][sks][lane] = packpos(ar0, ar1);
    __syncthreads();

    float dacc = 0.f;   // sum of winning dist' for my epilogue rows

    #pragma unroll
    for (int it = 0; it < NITER; ++it) {
        // prefetch next iter's staging slot under this iter's compute
        float4 br0, br1;
        if (it < NITER - 1) {
            const float* asrc = flat + (long)(rb + (it + 1) * 64 + srt * 16 + cb) * 64
                                + sks * 32 + (g << 3);
            br0 = *(const float4*)asrc;
            br1 = *(const float4*)(asrc + 4);
        }

        // ---- compute: 4 row-tiles x 4 code-tiles, B from VGPRs ----
        float pm[4][4];
        #pragma unroll
        for (int rt = 0; rt < 4; ++rt)
            #pragma unroll
            for (int j = 0; j < 4; ++j) pm[rt][j] = __builtin_bit_cast(float, 0x7F800000u);

        #pragma unroll
        for (int rt = 0; rt < 4; ++rt) {
            bf16x8 a0 = albuf[it & 1][rt][0][lane];
            bf16x8 a1 = albuf[it & 1][rt][1][lane];
            #pragma unroll
            for (int c = 0; c < 4; ++c) {
                const float h = hvv[c];
                const int colv = ((wid * 4 + c) << 4) | cb;
                f32x4 acc = {h, h, h, h};    // 0.5||e||^2 - x.e   (B = -e)
                acc = __builtin_amdgcn_mfma_f32_16x16x32_bf16(a0, bv[c][0], acc, 0, 0, 0);
                acc = __builtin_amdgcn_mfma_f32_16x16x32_bf16(a1, bv[c][1], acc, 0, 0, 0);
                #pragma unroll
                for (int j = 0; j < 4; ++j) {
                    uint32_t dp = (__builtin_bit_cast(uint32_t, acc[j]) & 0xFFFFFE00u) | (uint32_t)colv;
                    pm[rt][j] = fminf(pm[rt][j], __builtin_bit_cast(float, dp));
                }
            }
        }

        // ---- butterfly min over the 16 column-class lanes ----
        #pragma unroll
        for (int m = 1; m < 16; m <<= 1) {
            #pragma unroll
            for (int rt = 0; rt < 4; ++rt)
                #pragma unroll
                for (int j = 0; j < 4; ++j)
                    pm[rt][j] = fminf(pm[rt][j], __shfl_xor(pm[rt][j], m, 64));
        }
        if (cb == 0) {
            #pragma unroll
            for (int rt = 0; rt < 4; ++rt)
                #pragma unroll
                for (int j = 0; j < 4; ++j)
                    cmb[it & 1][wid][rt * 16 + g * 4 + j] = pm[rt][j];
        }

        // ---- stage next iter's A (rotating buffer, WAR-safe) ----
        if (it < NITER - 1) {
            xx = sumsq4(br0, xx); xx = sumsq4(br1, xx);
            albuf[(it + 1) & 1][srt][sks][lane] = packpos(br0, br1);
        }
        __syncthreads();   // cmb[it&1] + albuf[(it+1)&1] visible

        // ---- epilogue: row = tid>>3 (0..63), seg = tid&7 (8 floats) ----
        const int row = tid >> 3, seg = tid & 7;
        float mn = cmb[it & 1][0][row];
        #pragma unroll
        for (int w = 1; w < 8; ++w) mn = fminf(mn, cmb[it & 1][w][row]);
        const uint32_t mbits = __builtin_bit_cast(uint32_t, mn);
        const int ix = (int)(mbits & 0x1FFu);

        const float4* esrc = (const float4*)(emb + ix * 64 + seg * 8);
        float4 e0 = esrc[0], e1 = esrc[1];
        float* ob = out + 1 + (long)(rb + it * 64 + row) * 64 + seg * 8;
        ob[0] = e0.x; ob[1] = e0.y; ob[2] = e0.z; ob[3] = e0.w;
        ob[4] = e1.x; ob[5] = e1.y; ob[6] = e1.z; ob[7] = e1.w;

        if (seg == 0) dacc += __builtin_bit_cast(float, mbits & 0xFFFFFE00u);
    }

    // ---- loss partial: sum_threads( xx + 2*dacc ) ----
    float t = fmaf(2.f, dacc, xx);
    #pragma unroll
    for (int m = 32; m; m >>= 1) t += __shfl_down(t, m, 64);
    if (lane == 0) red[wid] = t;
    __syncthreads();
    if (tid == 0) {
        float s = 0.f;
        #pragma unroll
        for (int i = 0; i < 8; ++i) s += red[i];
        partials[bid] = s;
    }
}

// ---------------- Kernel 2: deterministic final reduce (1 block) ----------------
__global__ __launch_bounds__(256)
void vq_loss(const float* __restrict__ partials, float* __restrict__ out) {
    __shared__ float red[4];
    const int tid = threadIdx.x;
    float acc = partials[tid];
    #pragma unroll
    for (int m = 32; m; m >>= 1) acc += __shfl_down(acc, m, 64);
    if ((tid & 63) == 0) red[tid >> 6] = acc;
    __syncthreads();
    // loss = 0.25*e_loss + q_loss = 1.25 * mse (forward)
    if (tid == 0) out[0] = 1.25f * (red[0] + red[1] + red[2] + red[3]) / 4194304.0f;
}

extern "C" void kernel_launch(void* const* d_in, const int* in_sizes, int n_in,
                              void* d_out, int out_size, void* d_ws, size_t ws_size,
                              hipStream_t stream) {
    const float* flat = (const float*)d_in[0];   // [65536,64]
    const float* emb  = (const float*)d_in[1];   // [512,64]
    float* out = (float*)d_out;
    float* partials = (float*)d_ws;              // 256 floats

    vq_main<<<256, 512, 0, stream>>>(flat, emb, partials, out);
    vq_loss<<<1, 256, 0, stream>>>(partials, out);
}